// Round 4
// baseline (939.424 us; speedup 1.0000x reference)
//
#include <hip/hip_runtime.h>

#define BLK 256
#define BSHIFT 10
#define BSIZE 1024           // nodes per bucket (local index: 10 bits)
#define NSLICE 1024          // edge slices for hist/scatter
#define SCAN_T 512           // max K supported by single-block scan

template <typename T>
__device__ __forceinline__ T ntload(const T* p) { return __builtin_nontemporal_load(p); }

// ---------------- bucketed edge build (no global atomics) ----------------

// per-slice histogram of dst buckets -> partial[s][K]
__global__ void k_hist(const int* __restrict__ dst, int* __restrict__ partial,
                       int E, int chunk, int K) {
    extern __shared__ int cnt[];
    int s = blockIdx.x;
    for (int i = threadIdx.x; i < K; i += BLK) cnt[i] = 0;
    __syncthreads();
    int lo = s * chunk, hi = min(E, lo + chunk);
    for (int i = lo + threadIdx.x; i < hi; i += BLK)
        atomicAdd(&cnt[((unsigned)ntload(dst + i)) >> BSHIFT], 1);
    __syncthreads();
    int* prow = partial + (size_t)s * K;
    for (int i = threadIdx.x; i < K; i += BLK) prow[i] = cnt[i];
}

__global__ void k_totals(const int* __restrict__ partial, int* __restrict__ totals,
                         int S, int K) {
    int k = blockIdx.x * BLK + threadIdx.x;
    if (k >= K) return;
    int t = 0;
    for (int s = 0; s < S; ++s) t += partial[(size_t)s * K + k];
    totals[k] = t;
}

// exclusive scan of totals -> base[0..K]  (K <= SCAN_T)
__global__ void k_base(const int* __restrict__ totals, int* __restrict__ base, int K) {
    __shared__ int sh[SCAN_T];
    int t = threadIdx.x;
    int v = (t < K) ? totals[t] : 0;
    sh[t] = v;
    __syncthreads();
    for (int off = 1; off < SCAN_T; off <<= 1) {
        int u = (t >= off) ? sh[t - off] : 0;
        __syncthreads();
        sh[t] += u;
        __syncthreads();
    }
    if (t < K) base[t + 1] = sh[t];
    if (t == 0) base[0] = 0;
}

// per-bucket column scan: partial[s][k] -> base[k] + exclusive_sum_s
__global__ void __launch_bounds__(NSLICE) k_offsets(int* __restrict__ partial,
                                                    const int* __restrict__ base, int K) {
    __shared__ int sh[NSLICE];
    int k = blockIdx.x;
    int t = threadIdx.x;                  // blockDim.x == NSLICE
    int v = partial[(size_t)t * K + k];
    sh[t] = v;
    __syncthreads();
    for (int off = 1; off < NSLICE; off <<= 1) {
        int u = (t >= off) ? sh[t - off] : 0;
        __syncthreads();
        sh[t] += u;
        __syncthreads();
    }
    partial[(size_t)t * K + k] = base[k] + sh[t] - v;
}

// scatter: packed = (dst_local << sbits) | src
__global__ void k_scatter(const int* __restrict__ src, const int* __restrict__ dst,
                          const int* __restrict__ offs, int* __restrict__ packed,
                          int E, int chunk, int K, int sbits) {
    extern __shared__ int cur[];
    int s = blockIdx.x;
    const int* orow = offs + (size_t)s * K;
    for (int i = threadIdx.x; i < K; i += BLK) cur[i] = orow[i];
    __syncthreads();
    int lo = s * chunk, hi = min(E, lo + chunk);
    for (int i = lo + threadIdx.x; i < hi; i += BLK) {
        int d = ntload(dst + i);
        int sc = ntload(src + i);
        int pos = atomicAdd(&cur[d >> BSHIFT], 1);
        packed[pos] = ((d & (BSIZE - 1)) << sbits) | sc;
    }
}

// ---------------- aggregation passes (grid = K*M, private LDS tiles) -------

// degree counts -> degpart[b][BSIZE]
__global__ void k_deg(const int* __restrict__ packed, const int* __restrict__ base,
                      int M, int* __restrict__ degpart, int sbits) {
    __shared__ int cnt[BSIZE];
    int b = blockIdx.x;
    int k = b / M, m = b - k * M;
    for (int i = threadIdx.x; i < BSIZE; i += BLK) cnt[i] = 0;
    __syncthreads();
    int lo = base[k], len = base[k + 1] - lo;
    int l0 = lo + (int)(((long long)len * m) / M);
    int l1 = lo + (int)(((long long)len * (m + 1)) / M);
    for (int i = l0 + threadIdx.x; i < l1; i += BLK)
        atomicAdd(&cnt[((unsigned)ntload(packed + i)) >> sbits], 1);
    __syncthreads();
    int* outp = degpart + (size_t)b * BSIZE;
    for (int i = threadIdx.x; i < BSIZE; i += BLK) outp[i] = cnt[i];
}

// sum p[src] into private LDS tile -> partial[b][BSIZE][2]
__global__ void k_agg(const int* __restrict__ packed, const int* __restrict__ base,
                      int M, const float2* __restrict__ pin, float* __restrict__ partial,
                      int sbits, int smask) {
    __shared__ float acc[BSIZE * 2];
    int b = blockIdx.x;
    int k = b / M, m = b - k * M;
    for (int i = threadIdx.x; i < BSIZE * 2; i += BLK) acc[i] = 0.f;
    __syncthreads();
    int lo = base[k], len = base[k + 1] - lo;
    int l0 = lo + (int)(((long long)len * m) / M);
    int l1 = lo + (int)(((long long)len * (m + 1)) / M);
    for (int i = l0 + threadIdx.x; i < l1; i += BLK) {
        unsigned v = (unsigned)ntload(packed + i);
        int l = v >> sbits;
        float2 pv = pin[v & smask];
        atomicAdd(&acc[2 * l], pv.x);
        atomicAdd(&acc[2 * l + 1], pv.y);
    }
    __syncthreads();
    float* outp = partial + (size_t)b * (BSIZE * 2);
    for (int i = threadIdx.x * 4; i < BSIZE * 2; i += BLK * 4)
        *(float4*)(outp + i) = *(const float4*)(acc + i);
}

// ---------------- node epilogues ----------------

__global__ void k_node1(const int* __restrict__ degpart, int M,
                        const float* __restrict__ x, const float* __restrict__ W1,
                        float* __restrict__ dinv, float2* __restrict__ p1, int N) {
    int i = blockIdx.x * BLK + threadIdx.x;
    if (i >= N) return;
    int k = i >> BSHIFT, l = i & (BSIZE - 1);
    int c = 0;
    for (int m = 0; m < M; ++m) c += degpart[((size_t)(k * M + m)) * BSIZE + l];
    float di = rsqrtf((float)c + 1.0f);
    dinv[i] = di;
    float2 xv = ((const float2*)x)[i];
    float w00 = W1[0], w01 = W1[1], w10 = W1[2], w11 = W1[3];
    p1[i] = make_float2(di * (xv.x * w00 + xv.y * w10),
                        di * (xv.x * w01 + xv.y * w11));
}

__global__ void k_node_mid(const float* __restrict__ partial, int M,
                           const float* __restrict__ dinv, const float2* __restrict__ pin,
                           const float* __restrict__ b, const float* __restrict__ W,
                           float2* __restrict__ pout, int N) {
    int i = blockIdx.x * BLK + threadIdx.x;
    if (i >= N) return;
    int k = i >> BSHIFT, l = i & (BSIZE - 1);
    float2 self = pin[i];
    float ax = self.x, ay = self.y;
    for (int m = 0; m < M; ++m) {
        const float* pp = partial + ((size_t)(k * M + m)) * (BSIZE * 2) + 2 * l;
        ax += pp[0]; ay += pp[1];
    }
    float di = dinv[i];
    float h0 = fmaxf(fmaf(di, ax, b[0]), 0.f);
    float h1 = fmaxf(fmaf(di, ay, b[1]), 0.f);
    float w00 = W[0], w01 = W[1], w10 = W[2], w11 = W[3];
    pout[i] = make_float2(di * (h0 * w00 + h1 * w10),
                          di * (h0 * w01 + h1 * w11));
}

__global__ void k_out_init(float* __restrict__ out, const float* __restrict__ br, int G) {
    int i = blockIdx.x * BLK + threadIdx.x;
    if (i < G) out[i] = br[0];
}

// final layer epilogue fused with global_add_pool (sorted batch keys)
__global__ void k_node_final(const float* __restrict__ partial, int M,
                             const float* __restrict__ dinv, const float2* __restrict__ pin,
                             const float* __restrict__ b, const float* __restrict__ Wr,
                             const int* __restrict__ batch, float* __restrict__ out, int N) {
    int i = blockIdx.x * BLK + threadIdx.x;
    bool valid = i < N;
    float s = 0.f;
    int key = -1;
    if (valid) {
        int k = i >> BSHIFT, l = i & (BSIZE - 1);
        float2 self = pin[i];
        float ax = self.x, ay = self.y;
        for (int m = 0; m < M; ++m) {
            const float* pp = partial + ((size_t)(k * M + m)) * (BSIZE * 2) + 2 * l;
            ax += pp[0]; ay += pp[1];
        }
        float di = dinv[i];
        float h0 = fmaxf(fmaf(di, ax, b[0]), 0.f);
        float h1 = fmaxf(fmaf(di, ay, b[1]), 0.f);
        s = fmaf(h0, Wr[0], h1 * Wr[1]);
        key = batch[i];
    }
    int lane = threadIdx.x & 63;
    for (int off = 1; off < 64; off <<= 1) {
        float s2 = __shfl_down(s, off);
        int k2 = __shfl_down(key, off);
        if (lane + off < 64 && k2 == key) s += s2;
    }
    int kprev = __shfl_up(key, 1);
    if (valid && (lane == 0 || kprev != key)) unsafeAtomicAdd(&out[key], s);
}

// ---------------- launch ----------------

extern "C" void kernel_launch(void* const* d_in, const int* in_sizes, int n_in,
                              void* d_out, int out_size, void* d_ws, size_t ws_size,
                              hipStream_t stream) {
    const float* x    = (const float*)d_in[0];
    const int*   ei   = (const int*)d_in[1];
    const int*   batch= (const int*)d_in[2];
    const float* W1   = (const float*)d_in[3];
    const float* b1   = (const float*)d_in[4];
    const float* W2   = (const float*)d_in[5];
    const float* b2   = (const float*)d_in[6];
    const float* W3   = (const float*)d_in[7];
    const float* b3   = (const float*)d_in[8];
    const float* Wr   = (const float*)d_in[9];
    const float* br   = (const float*)d_in[10];
    float* out = (float*)d_out;

    int N = in_sizes[0] / 2;
    int E = in_sizes[1] / 2;
    int G = out_size;
    const int* src = ei;
    const int* dst = ei + E;

    int K = (N + BSIZE - 1) >> BSHIFT;
    if (K > SCAN_T) return;                     // unsupported shape -> fail loud
    int S = NSLICE;
    int chunk = (E + S - 1) / S;

    int sbits = 1;
    while ((1 << sbits) < N) ++sbits;           // src bit width (18 for N=200000)
    if (sbits + BSHIFT > 32) return;
    int smask = (1 << sbits) - 1;

    // pick M (sub-blocks per bucket) to fit workspace
    int M = 8;
    size_t need;
    for (;;) {
        need = (((size_t)E * 4 + 15) & ~(size_t)15)
             + (((size_t)S * K * 4 + 15) & ~(size_t)15)
             + (((size_t)(K + 1) * 4 + 15) & ~(size_t)15)
             + (((size_t)K * 4 + 15) & ~(size_t)15)
             + (((size_t)K * M * BSIZE * 2 * 4 + 15) & ~(size_t)15)
             + (((size_t)N * 4 + 15) & ~(size_t)15)
             + 2 * (((size_t)N * 8 + 15) & ~(size_t)15);
        if (need <= ws_size || M == 1) break;
        M >>= 1;
    }
    if (need > ws_size) return;

    char* w = (char*)d_ws;
    size_t off = 0;
    auto carve = [&](size_t bytes) { void* p = w + off; off += (bytes + 15) & ~(size_t)15; return p; };
    int*    packed  = (int*)carve((size_t)E * 4);
    int*    hpart   = (int*)carve((size_t)S * K * 4);
    int*    basep   = (int*)carve((size_t)(K + 1) * 4);
    int*    totals  = (int*)carve((size_t)K * 4);
    float*  aggpart = (float*)carve((size_t)K * M * BSIZE * 2 * 4);
    float*  dinv    = (float*)carve((size_t)N * 4);
    float2* pA      = (float2*)carve((size_t)N * 8);
    float2* pB      = (float2*)carve((size_t)N * 8);
    int*    degpart = (int*)aggpart;            // reuse: consumed before first k_agg

    int KB = (K + BLK - 1) / BLK;
    int NB = (N + BLK - 1) / BLK;
    int GB = (G + BLK - 1) / BLK;
    size_t smemK = (size_t)K * 4;
    int KM = K * M;

    // build bucketed edge list
    k_hist   <<<S, BLK, smemK, stream>>>(dst, hpart, E, chunk, K);
    k_totals <<<KB, BLK, 0, stream>>>(hpart, totals, S, K);
    k_base   <<<1, SCAN_T, 0, stream>>>(totals, basep, K);
    k_offsets<<<K, NSLICE, 0, stream>>>(hpart, basep, K);
    k_scatter<<<S, BLK, smemK, stream>>>(src, dst, hpart, packed, E, chunk, K, sbits);

    // degree -> dinv, p1
    k_deg   <<<KM, BLK, 0, stream>>>(packed, basep, M, degpart, sbits);
    k_node1 <<<NB, BLK, 0, stream>>>(degpart, M, x, W1, dinv, pA, N);

    // layer 1
    k_agg     <<<KM, BLK, 0, stream>>>(packed, basep, M, pA, aggpart, sbits, smask);
    k_node_mid<<<NB, BLK, 0, stream>>>(aggpart, M, dinv, pA, b1, W2, pB, N);
    // layer 2
    k_agg     <<<KM, BLK, 0, stream>>>(packed, basep, M, pB, aggpart, sbits, smask);
    k_node_mid<<<NB, BLK, 0, stream>>>(aggpart, M, dinv, pB, b2, W3, pA, N);
    // layer 3 + pool
    k_agg     <<<KM, BLK, 0, stream>>>(packed, basep, M, pA, aggpart, sbits, smask);
    k_out_init<<<GB, BLK, 0, stream>>>(out, br, G);
    k_node_final<<<NB, BLK, 0, stream>>>(aggpart, M, dinv, pA, b3, Wr, batch, out, N);
}

// Round 5
// 701.728 us; speedup vs baseline: 1.3387x; 1.3387x over previous
//
#include <hip/hip_runtime.h>

#define BLK 256
#define BSHIFT 10
#define BSIZE 1024           // nodes per bucket (local index: 10 bits)
#define NSLICE 1024          // edge slices for hist/scatter
#define SCAN_T 512           // max K supported by single-block scan

template <typename T>
__device__ __forceinline__ T ntload(const T* p) { return __builtin_nontemporal_load(p); }

// ---------------- bucketed edge build (no global atomics) ----------------

// per-slice histogram of dst buckets -> partial[s][K]
__global__ void k_hist(const int* __restrict__ dst, int* __restrict__ partial,
                       int E, int chunk, int K) {
    extern __shared__ int cnt[];
    int s = blockIdx.x;
    for (int i = threadIdx.x; i < K; i += BLK) cnt[i] = 0;
    __syncthreads();
    int lo = s * chunk, hi = min(E, lo + chunk);
    for (int i = lo + threadIdx.x; i < hi; i += BLK)
        atomicAdd(&cnt[((unsigned)ntload(dst + i)) >> BSHIFT], 1);
    __syncthreads();
    int* prow = partial + (size_t)s * K;
    for (int i = threadIdx.x; i < K; i += BLK) prow[i] = cnt[i];
}

// per-bucket column scan: partial[s][k] -> exclusive prefix (local), totals[k] = column sum
__global__ void __launch_bounds__(NSLICE) k_colscan(int* __restrict__ partial,
                                                    int* __restrict__ totals, int K) {
    __shared__ int sh[NSLICE];
    int k = blockIdx.x;
    int t = threadIdx.x;                  // blockDim.x == NSLICE
    int v = partial[(size_t)t * K + k];
    sh[t] = v;
    __syncthreads();
    for (int off = 1; off < NSLICE; off <<= 1) {
        int u = (t >= off) ? sh[t - off] : 0;
        __syncthreads();
        sh[t] += u;
        __syncthreads();
    }
    partial[(size_t)t * K + k] = sh[t] - v;       // exclusive, base added in scatter
    if (t == NSLICE - 1) totals[k] = sh[t];
}

// exclusive scan of totals -> base[0..K]  (K <= SCAN_T)
__global__ void k_base(const int* __restrict__ totals, int* __restrict__ base, int K) {
    __shared__ int sh[SCAN_T];
    int t = threadIdx.x;
    int v = (t < K) ? totals[t] : 0;
    sh[t] = v;
    __syncthreads();
    for (int off = 1; off < SCAN_T; off <<= 1) {
        int u = (t >= off) ? sh[t - off] : 0;
        __syncthreads();
        sh[t] += u;
        __syncthreads();
    }
    if (t < K) base[t + 1] = sh[t];
    if (t == 0) base[0] = 0;
}

// scatter: packed = (dst_local << sbits) | src
__global__ void k_scatter(const int* __restrict__ src, const int* __restrict__ dst,
                          const int* __restrict__ offs, const int* __restrict__ base,
                          int* __restrict__ packed, int E, int chunk, int K, int sbits) {
    extern __shared__ int cur[];
    int s = blockIdx.x;
    const int* orow = offs + (size_t)s * K;
    for (int i = threadIdx.x; i < K; i += BLK) cur[i] = orow[i] + base[i];
    __syncthreads();
    int lo = s * chunk, hi = min(E, lo + chunk);
    for (int i = lo + threadIdx.x; i < hi; i += BLK) {
        int d = ntload(dst + i);
        int sc = ntload(src + i);
        int pos = atomicAdd(&cur[d >> BSHIFT], 1);
        packed[pos] = ((d & (BSIZE - 1)) << sbits) | sc;
    }
}

// ---------------- aggregation passes (grid = K*M, private LDS tiles) -------

// degree counts -> degpart[b][BSIZE]
__global__ void k_deg(const int* __restrict__ packed, const int* __restrict__ base,
                      int M, int* __restrict__ degpart, int sbits) {
    __shared__ int cnt[BSIZE];
    int b = blockIdx.x;
    int k = b / M, m = b - k * M;
    for (int i = threadIdx.x; i < BSIZE; i += BLK) cnt[i] = 0;
    __syncthreads();
    int lo = base[k], len = base[k + 1] - lo;
    int l0 = lo + (int)(((long long)len * m) / M);
    int l1 = lo + (int)(((long long)len * (m + 1)) / M);
    for (int i = l0 + threadIdx.x; i < l1; i += BLK)
        atomicAdd(&cnt[((unsigned)ntload(packed + i)) >> sbits], 1);
    __syncthreads();
    int* outp = degpart + (size_t)b * BSIZE;
    for (int i = threadIdx.x; i < BSIZE; i += BLK) outp[i] = cnt[i];
}

// sum p[src] into private LDS tile -> partial[b][BSIZE][2]
__global__ void k_agg(const int* __restrict__ packed, const int* __restrict__ base,
                      int M, const float2* __restrict__ pin, float* __restrict__ partial,
                      int sbits, int smask) {
    __shared__ float acc[BSIZE * 2];
    int b = blockIdx.x;
    int k = b / M, m = b - k * M;
    for (int i = threadIdx.x; i < BSIZE * 2; i += BLK) acc[i] = 0.f;
    __syncthreads();
    int lo = base[k], len = base[k + 1] - lo;
    int l0 = lo + (int)(((long long)len * m) / M);
    int l1 = lo + (int)(((long long)len * (m + 1)) / M);
    for (int i = l0 + threadIdx.x; i < l1; i += BLK) {
        unsigned v = (unsigned)ntload(packed + i);
        int l = v >> sbits;
        float2 pv = pin[v & smask];
        atomicAdd(&acc[2 * l], pv.x);
        atomicAdd(&acc[2 * l + 1], pv.y);
    }
    __syncthreads();
    float* outp = partial + (size_t)b * (BSIZE * 2);
    for (int i = threadIdx.x * 4; i < BSIZE * 2; i += BLK * 4)
        *(float4*)(outp + i) = *(const float4*)(acc + i);
}

// ---------------- node epilogues ----------------

__global__ void k_node1(const int* __restrict__ degpart, int M,
                        const float* __restrict__ x, const float* __restrict__ W1,
                        float* __restrict__ dinv, float2* __restrict__ p1, int N) {
    int i = blockIdx.x * BLK + threadIdx.x;
    if (i >= N) return;
    int k = i >> BSHIFT, l = i & (BSIZE - 1);
    int c = 0;
    for (int m = 0; m < M; ++m) c += degpart[((size_t)(k * M + m)) * BSIZE + l];
    float di = rsqrtf((float)c + 1.0f);
    dinv[i] = di;
    float2 xv = ((const float2*)x)[i];
    float w00 = W1[0], w01 = W1[1], w10 = W1[2], w11 = W1[3];
    p1[i] = make_float2(di * (xv.x * w00 + xv.y * w10),
                        di * (xv.x * w01 + xv.y * w11));
}

__global__ void k_node_mid(const float* __restrict__ partial, int M,
                           const float* __restrict__ dinv, const float2* __restrict__ pin,
                           const float* __restrict__ b, const float* __restrict__ W,
                           float2* __restrict__ pout, int N) {
    int i = blockIdx.x * BLK + threadIdx.x;
    if (i >= N) return;
    int k = i >> BSHIFT, l = i & (BSIZE - 1);
    float2 self = pin[i];
    float ax = self.x, ay = self.y;
    for (int m = 0; m < M; ++m) {
        const float* pp = partial + ((size_t)(k * M + m)) * (BSIZE * 2) + 2 * l;
        ax += pp[0]; ay += pp[1];
    }
    float di = dinv[i];
    float h0 = fmaxf(fmaf(di, ax, b[0]), 0.f);
    float h1 = fmaxf(fmaf(di, ay, b[1]), 0.f);
    float w00 = W[0], w01 = W[1], w10 = W[2], w11 = W[3];
    pout[i] = make_float2(di * (h0 * w00 + h1 * w10),
                          di * (h0 * w01 + h1 * w11));
}

__global__ void k_out_init(float* __restrict__ out, const float* __restrict__ br, int G) {
    int i = blockIdx.x * BLK + threadIdx.x;
    if (i < G) out[i] = br[0];
}

// final layer epilogue fused with global_add_pool (sorted batch keys)
__global__ void k_node_final(const float* __restrict__ partial, int M,
                             const float* __restrict__ dinv, const float2* __restrict__ pin,
                             const float* __restrict__ b, const float* __restrict__ Wr,
                             const int* __restrict__ batch, float* __restrict__ out, int N) {
    int i = blockIdx.x * BLK + threadIdx.x;
    bool valid = i < N;
    float s = 0.f;
    int key = -1;
    if (valid) {
        int k = i >> BSHIFT, l = i & (BSIZE - 1);
        float2 self = pin[i];
        float ax = self.x, ay = self.y;
        for (int m = 0; m < M; ++m) {
            const float* pp = partial + ((size_t)(k * M + m)) * (BSIZE * 2) + 2 * l;
            ax += pp[0]; ay += pp[1];
        }
        float di = dinv[i];
        float h0 = fmaxf(fmaf(di, ax, b[0]), 0.f);
        float h1 = fmaxf(fmaf(di, ay, b[1]), 0.f);
        s = fmaf(h0, Wr[0], h1 * Wr[1]);
        key = batch[i];
    }
    int lane = threadIdx.x & 63;
    for (int off = 1; off < 64; off <<= 1) {
        float s2 = __shfl_down(s, off);
        int k2 = __shfl_down(key, off);
        if (lane + off < 64 && k2 == key) s += s2;
    }
    int kprev = __shfl_up(key, 1);
    if (valid && (lane == 0 || kprev != key)) unsafeAtomicAdd(&out[key], s);
}

// ---------------- launch ----------------

extern "C" void kernel_launch(void* const* d_in, const int* in_sizes, int n_in,
                              void* d_out, int out_size, void* d_ws, size_t ws_size,
                              hipStream_t stream) {
    const float* x    = (const float*)d_in[0];
    const int*   ei   = (const int*)d_in[1];
    const int*   batch= (const int*)d_in[2];
    const float* W1   = (const float*)d_in[3];
    const float* b1   = (const float*)d_in[4];
    const float* W2   = (const float*)d_in[5];
    const float* b2   = (const float*)d_in[6];
    const float* W3   = (const float*)d_in[7];
    const float* b3   = (const float*)d_in[8];
    const float* Wr   = (const float*)d_in[9];
    const float* br   = (const float*)d_in[10];
    float* out = (float*)d_out;

    int N = in_sizes[0] / 2;
    int E = in_sizes[1] / 2;
    int G = out_size;
    const int* src = ei;
    const int* dst = ei + E;

    int K = (N + BSIZE - 1) >> BSHIFT;
    if (K > SCAN_T) return;                     // unsupported shape -> fail loud
    int S = NSLICE;
    int chunk = (E + S - 1) / S;

    int sbits = 1;
    while ((1 << sbits) < N) ++sbits;           // src bit width (18 for N=200000)
    if (sbits + BSHIFT > 32) return;
    int smask = (1 << sbits) - 1;

    // pick M (sub-blocks per bucket) to fit workspace
    int M = 8;
    size_t need;
    for (;;) {
        need = (((size_t)E * 4 + 15) & ~(size_t)15)
             + (((size_t)S * K * 4 + 15) & ~(size_t)15)
             + (((size_t)(K + 1) * 4 + 15) & ~(size_t)15)
             + (((size_t)K * 4 + 15) & ~(size_t)15)
             + (((size_t)K * M * BSIZE * 2 * 4 + 15) & ~(size_t)15)
             + (((size_t)N * 4 + 15) & ~(size_t)15)
             + 2 * (((size_t)N * 8 + 15) & ~(size_t)15);
        if (need <= ws_size || M == 1) break;
        M >>= 1;
    }
    if (need > ws_size) return;

    char* w = (char*)d_ws;
    size_t off = 0;
    auto carve = [&](size_t bytes) { void* p = w + off; off += (bytes + 15) & ~(size_t)15; return p; };
    int*    packed  = (int*)carve((size_t)E * 4);
    int*    hpart   = (int*)carve((size_t)S * K * 4);
    int*    basep   = (int*)carve((size_t)(K + 1) * 4);
    int*    totals  = (int*)carve((size_t)K * 4);
    float*  aggpart = (float*)carve((size_t)K * M * BSIZE * 2 * 4);
    float*  dinv    = (float*)carve((size_t)N * 4);
    float2* pA      = (float2*)carve((size_t)N * 8);
    float2* pB      = (float2*)carve((size_t)N * 8);
    int*    degpart = (int*)aggpart;            // reuse: consumed before first k_agg

    int NB = (N + BLK - 1) / BLK;
    int GB = (G + BLK - 1) / BLK;
    size_t smemK = (size_t)K * 4;
    int KM = K * M;

    // build bucketed edge list
    k_hist   <<<S, BLK, smemK, stream>>>(dst, hpart, E, chunk, K);
    k_colscan<<<K, NSLICE, 0, stream>>>(hpart, totals, K);
    k_base   <<<1, SCAN_T, 0, stream>>>(totals, basep, K);
    k_scatter<<<S, BLK, smemK, stream>>>(src, dst, hpart, basep, packed, E, chunk, K, sbits);

    // degree -> dinv, p1
    k_deg   <<<KM, BLK, 0, stream>>>(packed, basep, M, degpart, sbits);
    k_node1 <<<NB, BLK, 0, stream>>>(degpart, M, x, W1, dinv, pA, N);

    // layer 1
    k_agg     <<<KM, BLK, 0, stream>>>(packed, basep, M, pA, aggpart, sbits, smask);
    k_node_mid<<<NB, BLK, 0, stream>>>(aggpart, M, dinv, pA, b1, W2, pB, N);
    // layer 2
    k_agg     <<<KM, BLK, 0, stream>>>(packed, basep, M, pB, aggpart, sbits, smask);
    k_node_mid<<<NB, BLK, 0, stream>>>(aggpart, M, dinv, pB, b2, W3, pA, N);
    // layer 3 + pool
    k_agg     <<<KM, BLK, 0, stream>>>(packed, basep, M, pA, aggpart, sbits, smask);
    k_out_init<<<GB, BLK, 0, stream>>>(out, br, G);
    k_node_final<<<NB, BLK, 0, stream>>>(aggpart, M, dinv, pA, b3, Wr, batch, out, N);
}

// Round 6
// 599.709 us; speedup vs baseline: 1.5665x; 1.1701x over previous
//
#include <hip/hip_runtime.h>

#define BLK 256
#define BSHIFT 10
#define BSIZE 1024           // nodes per bucket (local index: 10 bits)
#define NSLICE 1024          // edge slices for hist/scatter
#define SCAN_T 512           // max K supported by single-block scan
#define KPAD 256             // max buckets (scan width in k_scatter)
#define EPT 8                // edges per thread per tile in k_scatter
#define TILE (BLK * EPT)     // 2048 edges staged per tile

template <typename T>
__device__ __forceinline__ T ntload(const T* p) { return __builtin_nontemporal_load(p); }

// ---------------- bucketed edge build (no global atomics) ----------------

// per-slice histogram of dst buckets -> partial[s][K]
__global__ void k_hist(const int* __restrict__ dst, int* __restrict__ partial,
                       int E, int chunk, int K) {
    extern __shared__ int cnt[];
    int s = blockIdx.x;
    for (int i = threadIdx.x; i < K; i += BLK) cnt[i] = 0;
    __syncthreads();
    int lo = s * chunk, hi = min(E, lo + chunk);
    for (int i = lo + threadIdx.x; i < hi; i += BLK)
        atomicAdd(&cnt[((unsigned)ntload(dst + i)) >> BSHIFT], 1);
    __syncthreads();
    int* prow = partial + (size_t)s * K;
    for (int i = threadIdx.x; i < K; i += BLK) prow[i] = cnt[i];
}

// per-bucket column scan: partial[s][k] -> exclusive prefix (local), totals[k] = column sum
__global__ void __launch_bounds__(NSLICE) k_colscan(int* __restrict__ partial,
                                                    int* __restrict__ totals, int K) {
    __shared__ int sh[NSLICE];
    int k = blockIdx.x;
    int t = threadIdx.x;                  // blockDim.x == NSLICE
    int v = partial[(size_t)t * K + k];
    sh[t] = v;
    __syncthreads();
    for (int off = 1; off < NSLICE; off <<= 1) {
        int u = (t >= off) ? sh[t - off] : 0;
        __syncthreads();
        sh[t] += u;
        __syncthreads();
    }
    partial[(size_t)t * K + k] = sh[t] - v;       // exclusive, base added in scatter
    if (t == NSLICE - 1) totals[k] = sh[t];
}

// exclusive scan of totals -> base[0..K]  (K <= SCAN_T)
__global__ void k_base(const int* __restrict__ totals, int* __restrict__ base, int K) {
    __shared__ int sh[SCAN_T];
    int t = threadIdx.x;
    int v = (t < K) ? totals[t] : 0;
    sh[t] = v;
    __syncthreads();
    for (int off = 1; off < SCAN_T; off <<= 1) {
        int u = (t >= off) ? sh[t - off] : 0;
        __syncthreads();
        sh[t] += u;
        __syncthreads();
    }
    if (t < K) base[t + 1] = sh[t];
    if (t == 0) base[0] = 0;
}

// tile counting-sort scatter: stage bucket-ordered in LDS, burst-flush coalesced.
// packed = (dst_local << sbits) | src
__global__ void __launch_bounds__(BLK) k_scatter(const int* __restrict__ src,
                                                 const int* __restrict__ dst,
                                                 const int* __restrict__ offs,
                                                 const int* __restrict__ base,
                                                 int* __restrict__ packed,
                                                 int E, int chunk, int K, int sbits) {
    __shared__ int cnt[KPAD];
    __shared__ int scn[KPAD];
    __shared__ int gstart[KPAD];
    __shared__ int cur[KPAD];
    __shared__ int stageval[TILE];
    __shared__ int stageaddr[TILE];
    int s = blockIdx.x;
    int tid = threadIdx.x;
    const int* orow = offs + (size_t)s * K;
    if (tid < K) cur[tid] = orow[tid] + base[tid];   // deterministic range start
    int lo = s * chunk, hi = min(E, lo + chunk);

    for (int tlo = lo; tlo < hi; tlo += TILE) {
        for (int k2 = tid; k2 < KPAD; k2 += BLK) cnt[k2] = 0;
        __syncthreads();

        int kk[EPT], rr[EPT], vv[EPT];
#pragma unroll
        for (int j = 0; j < EPT; ++j) {
            int i = tlo + j * BLK + tid;
            kk[j] = -1;
            if (i < hi) {
                int d = ntload(dst + i);
                int sc = ntload(src + i);
                kk[j] = ((unsigned)d) >> BSHIFT;
                vv[j] = ((d & (BSIZE - 1)) << sbits) | sc;
                rr[j] = atomicAdd(&cnt[kk[j]], 1);
            }
        }
        __syncthreads();

        // block-wide exclusive scan over cnt (KPAD == BLK)
        int c = cnt[tid];
        scn[tid] = c;
        __syncthreads();
        for (int off = 1; off < KPAD; off <<= 1) {
            int u = (tid >= off) ? scn[tid - off] : 0;
            __syncthreads();
            scn[tid] += u;
            __syncthreads();
        }
        scn[tid] -= c;                 // exclusive
        gstart[tid] = cur[tid];        // reserve global range for this tile
        cur[tid] += c;
        __syncthreads();

        // stage bucket-ordered
#pragma unroll
        for (int j = 0; j < EPT; ++j) {
            if (kk[j] >= 0) {
                int idx = scn[kk[j]] + rr[j];
                stageval[idx]  = vv[j];
                stageaddr[idx] = gstart[kk[j]] + rr[j];
            }
        }
        __syncthreads();

        // burst flush: consecutive threads -> consecutive addresses per segment
        int tot = min(hi - tlo, TILE);
        for (int i2 = tid; i2 < tot; i2 += BLK)
            packed[stageaddr[i2]] = stageval[i2];
        __syncthreads();
    }
}

// ---------------- aggregation passes (grid = K*M, private LDS tiles) -------

// degree counts -> degpart[b][BSIZE]
__global__ void k_deg(const int* __restrict__ packed, const int* __restrict__ base,
                      int M, int* __restrict__ degpart, int sbits) {
    __shared__ int cnt[BSIZE];
    int b = blockIdx.x;
    int k = b / M, m = b - k * M;
    for (int i = threadIdx.x; i < BSIZE; i += BLK) cnt[i] = 0;
    __syncthreads();
    int lo = base[k], len = base[k + 1] - lo;
    int l0 = lo + (int)(((long long)len * m) / M);
    int l1 = lo + (int)(((long long)len * (m + 1)) / M);
    for (int i = l0 + threadIdx.x; i < l1; i += BLK)
        atomicAdd(&cnt[((unsigned)ntload(packed + i)) >> sbits], 1);
    __syncthreads();
    int* outp = degpart + (size_t)b * BSIZE;
    for (int i = threadIdx.x; i < BSIZE; i += BLK) outp[i] = cnt[i];
}

// sum p[src] into private LDS tile -> partial[b][BSIZE][2]
__global__ void k_agg(const int* __restrict__ packed, const int* __restrict__ base,
                      int M, const float2* __restrict__ pin, float* __restrict__ partial,
                      int sbits, int smask) {
    __shared__ float acc[BSIZE * 2];
    int b = blockIdx.x;
    int k = b / M, m = b - k * M;
    for (int i = threadIdx.x; i < BSIZE * 2; i += BLK) acc[i] = 0.f;
    __syncthreads();
    int lo = base[k], len = base[k + 1] - lo;
    int l0 = lo + (int)(((long long)len * m) / M);
    int l1 = lo + (int)(((long long)len * (m + 1)) / M);
    for (int i = l0 + threadIdx.x; i < l1; i += BLK) {
        unsigned v = (unsigned)ntload(packed + i);
        int l = v >> sbits;
        float2 pv = pin[v & smask];
        atomicAdd(&acc[2 * l], pv.x);
        atomicAdd(&acc[2 * l + 1], pv.y);
    }
    __syncthreads();
    float* outp = partial + (size_t)b * (BSIZE * 2);
    for (int i = threadIdx.x * 4; i < BSIZE * 2; i += BLK * 4)
        *(float4*)(outp + i) = *(const float4*)(acc + i);
}

// ---------------- node epilogues ----------------

__global__ void k_node1(const int* __restrict__ degpart, int M,
                        const float* __restrict__ x, const float* __restrict__ W1,
                        float* __restrict__ dinv, float2* __restrict__ p1, int N) {
    int i = blockIdx.x * BLK + threadIdx.x;
    if (i >= N) return;
    int k = i >> BSHIFT, l = i & (BSIZE - 1);
    int c = 0;
    for (int m = 0; m < M; ++m) c += degpart[((size_t)(k * M + m)) * BSIZE + l];
    float di = rsqrtf((float)c + 1.0f);
    dinv[i] = di;
    float2 xv = ((const float2*)x)[i];
    float w00 = W1[0], w01 = W1[1], w10 = W1[2], w11 = W1[3];
    p1[i] = make_float2(di * (xv.x * w00 + xv.y * w10),
                        di * (xv.x * w01 + xv.y * w11));
}

__global__ void k_node_mid(const float* __restrict__ partial, int M,
                           const float* __restrict__ dinv, const float2* __restrict__ pin,
                           const float* __restrict__ b, const float* __restrict__ W,
                           float2* __restrict__ pout, int N) {
    int i = blockIdx.x * BLK + threadIdx.x;
    if (i >= N) return;
    int k = i >> BSHIFT, l = i & (BSIZE - 1);
    float2 self = pin[i];
    float ax = self.x, ay = self.y;
    for (int m = 0; m < M; ++m) {
        const float* pp = partial + ((size_t)(k * M + m)) * (BSIZE * 2) + 2 * l;
        ax += pp[0]; ay += pp[1];
    }
    float di = dinv[i];
    float h0 = fmaxf(fmaf(di, ax, b[0]), 0.f);
    float h1 = fmaxf(fmaf(di, ay, b[1]), 0.f);
    float w00 = W[0], w01 = W[1], w10 = W[2], w11 = W[3];
    pout[i] = make_float2(di * (h0 * w00 + h1 * w10),
                          di * (h0 * w01 + h1 * w11));
}

__global__ void k_out_init(float* __restrict__ out, const float* __restrict__ br, int G) {
    int i = blockIdx.x * BLK + threadIdx.x;
    if (i < G) out[i] = br[0];
}

// final layer epilogue fused with global_add_pool (sorted batch keys)
__global__ void k_node_final(const float* __restrict__ partial, int M,
                             const float* __restrict__ dinv, const float2* __restrict__ pin,
                             const float* __restrict__ b, const float* __restrict__ Wr,
                             const int* __restrict__ batch, float* __restrict__ out, int N) {
    int i = blockIdx.x * BLK + threadIdx.x;
    bool valid = i < N;
    float s = 0.f;
    int key = -1;
    if (valid) {
        int k = i >> BSHIFT, l = i & (BSIZE - 1);
        float2 self = pin[i];
        float ax = self.x, ay = self.y;
        for (int m = 0; m < M; ++m) {
            const float* pp = partial + ((size_t)(k * M + m)) * (BSIZE * 2) + 2 * l;
            ax += pp[0]; ay += pp[1];
        }
        float di = dinv[i];
        float h0 = fmaxf(fmaf(di, ax, b[0]), 0.f);
        float h1 = fmaxf(fmaf(di, ay, b[1]), 0.f);
        s = fmaf(h0, Wr[0], h1 * Wr[1]);
        key = batch[i];
    }
    int lane = threadIdx.x & 63;
    for (int off = 1; off < 64; off <<= 1) {
        float s2 = __shfl_down(s, off);
        int k2 = __shfl_down(key, off);
        if (lane + off < 64 && k2 == key) s += s2;
    }
    int kprev = __shfl_up(key, 1);
    if (valid && (lane == 0 || kprev != key)) unsafeAtomicAdd(&out[key], s);
}

// ---------------- launch ----------------

extern "C" void kernel_launch(void* const* d_in, const int* in_sizes, int n_in,
                              void* d_out, int out_size, void* d_ws, size_t ws_size,
                              hipStream_t stream) {
    const float* x    = (const float*)d_in[0];
    const int*   ei   = (const int*)d_in[1];
    const int*   batch= (const int*)d_in[2];
    const float* W1   = (const float*)d_in[3];
    const float* b1   = (const float*)d_in[4];
    const float* W2   = (const float*)d_in[5];
    const float* b2   = (const float*)d_in[6];
    const float* W3   = (const float*)d_in[7];
    const float* b3   = (const float*)d_in[8];
    const float* Wr   = (const float*)d_in[9];
    const float* br   = (const float*)d_in[10];
    float* out = (float*)d_out;

    int N = in_sizes[0] / 2;
    int E = in_sizes[1] / 2;
    int G = out_size;
    const int* src = ei;
    const int* dst = ei + E;

    int K = (N + BSIZE - 1) >> BSHIFT;
    if (K > KPAD) return;                       // scatter scan width limit
    int S = NSLICE;
    int chunk = (E + S - 1) / S;

    int sbits = 1;
    while ((1 << sbits) < N) ++sbits;           // src bit width (18 for N=200000)
    if (sbits + BSHIFT > 32) return;
    int smask = (1 << sbits) - 1;

    // pick M (sub-blocks per bucket) to fit workspace
    int M = 8;
    size_t need;
    for (;;) {
        need = (((size_t)E * 4 + 15) & ~(size_t)15)
             + (((size_t)S * K * 4 + 15) & ~(size_t)15)
             + (((size_t)(K + 1) * 4 + 15) & ~(size_t)15)
             + (((size_t)K * 4 + 15) & ~(size_t)15)
             + (((size_t)K * M * BSIZE * 2 * 4 + 15) & ~(size_t)15)
             + (((size_t)N * 4 + 15) & ~(size_t)15)
             + 2 * (((size_t)N * 8 + 15) & ~(size_t)15);
        if (need <= ws_size || M == 1) break;
        M >>= 1;
    }
    if (need > ws_size) return;

    char* w = (char*)d_ws;
    size_t off = 0;
    auto carve = [&](size_t bytes) { void* p = w + off; off += (bytes + 15) & ~(size_t)15; return p; };
    int*    packed  = (int*)carve((size_t)E * 4);
    int*    hpart   = (int*)carve((size_t)S * K * 4);
    int*    basep   = (int*)carve((size_t)(K + 1) * 4);
    int*    totals  = (int*)carve((size_t)K * 4);
    float*  aggpart = (float*)carve((size_t)K * M * BSIZE * 2 * 4);
    float*  dinv    = (float*)carve((size_t)N * 4);
    float2* pA      = (float2*)carve((size_t)N * 8);
    float2* pB      = (float2*)carve((size_t)N * 8);
    int*    degpart = (int*)aggpart;            // reuse: consumed before first k_agg

    int NB = (N + BLK - 1) / BLK;
    int GB = (G + BLK - 1) / BLK;
    size_t smemK = (size_t)K * 4;
    int KM = K * M;

    // build bucketed edge list
    k_hist   <<<S, BLK, smemK, stream>>>(dst, hpart, E, chunk, K);
    k_colscan<<<K, NSLICE, 0, stream>>>(hpart, totals, K);
    k_base   <<<1, SCAN_T, 0, stream>>>(totals, basep, K);
    k_scatter<<<S, BLK, 0, stream>>>(src, dst, hpart, basep, packed, E, chunk, K, sbits);

    // degree -> dinv, p1
    k_deg   <<<KM, BLK, 0, stream>>>(packed, basep, M, degpart, sbits);
    k_node1 <<<NB, BLK, 0, stream>>>(degpart, M, x, W1, dinv, pA, N);

    // layer 1
    k_agg     <<<KM, BLK, 0, stream>>>(packed, basep, M, pA, aggpart, sbits, smask);
    k_node_mid<<<NB, BLK, 0, stream>>>(aggpart, M, dinv, pA, b1, W2, pB, N);
    // layer 2
    k_agg     <<<KM, BLK, 0, stream>>>(packed, basep, M, pB, aggpart, sbits, smask);
    k_node_mid<<<NB, BLK, 0, stream>>>(aggpart, M, dinv, pB, b2, W3, pA, N);
    // layer 3 + pool
    k_agg     <<<KM, BLK, 0, stream>>>(packed, basep, M, pA, aggpart, sbits, smask);
    k_out_init<<<GB, BLK, 0, stream>>>(out, br, G);
    k_node_final<<<NB, BLK, 0, stream>>>(aggpart, M, dinv, pA, b3, Wr, batch, out, N);
}

// Round 8
// 576.728 us; speedup vs baseline: 1.6289x; 1.0398x over previous
//
#include <hip/hip_runtime.h>

#define BLK 256
#define BSHIFT 10
#define BSIZE 1024           // nodes per bucket (local index: 10 bits)
#define NSLICE 1024          // edge slices for hist/scatter
#define SCAN_T 512           // max K supported by single-block scan
#define KPAD 256             // max buckets (scan width in k_scatter)
#define EPT 8                // edges per thread per tile in k_scatter
#define TILE (BLK * EPT)     // 2048 edges staged per tile

typedef int iv4 __attribute__((ext_vector_type(4)));   // clang vector: nt-load legal

template <typename T>
__device__ __forceinline__ T ntload(const T* p) { return __builtin_nontemporal_load(p); }

__device__ __forceinline__ iv4 ntload4(const int* p) {
    return __builtin_nontemporal_load((const iv4*)p);
}

// ---------------- bucketed edge build (no global atomics) ----------------

// per-slice histogram of dst buckets -> partial[s][K]
__global__ void k_hist(const int* __restrict__ dst, int* __restrict__ partial,
                       int E, int chunk, int K) {
    extern __shared__ int cnt[];
    int s = blockIdx.x;
    for (int i = threadIdx.x; i < K; i += BLK) cnt[i] = 0;
    __syncthreads();
    int lo = s * chunk, hi = min(E, lo + chunk);
    for (int i = lo + threadIdx.x; i < hi; i += BLK)
        atomicAdd(&cnt[((unsigned)ntload(dst + i)) >> BSHIFT], 1);
    __syncthreads();
    int* prow = partial + (size_t)s * K;
    for (int i = threadIdx.x; i < K; i += BLK) prow[i] = cnt[i];
}

// per-bucket column scan: partial[s][k] -> exclusive prefix (local), totals[k] = column sum
__global__ void __launch_bounds__(NSLICE) k_colscan(int* __restrict__ partial,
                                                    int* __restrict__ totals, int K) {
    __shared__ int sh[NSLICE];
    int k = blockIdx.x;
    int t = threadIdx.x;                  // blockDim.x == NSLICE
    int v = partial[(size_t)t * K + k];
    sh[t] = v;
    __syncthreads();
    for (int off = 1; off < NSLICE; off <<= 1) {
        int u = (t >= off) ? sh[t - off] : 0;
        __syncthreads();
        sh[t] += u;
        __syncthreads();
    }
    partial[(size_t)t * K + k] = sh[t] - v;       // exclusive, base added in scatter
    if (t == NSLICE - 1) totals[k] = sh[t];
}

// exclusive scan of totals -> base[0..K]  (K <= SCAN_T)
__global__ void k_base(const int* __restrict__ totals, int* __restrict__ base, int K) {
    __shared__ int sh[SCAN_T];
    int t = threadIdx.x;
    int v = (t < K) ? totals[t] : 0;
    sh[t] = v;
    __syncthreads();
    for (int off = 1; off < SCAN_T; off <<= 1) {
        int u = (t >= off) ? sh[t - off] : 0;
        __syncthreads();
        sh[t] += u;
        __syncthreads();
    }
    if (t < K) base[t + 1] = sh[t];
    if (t == 0) base[0] = 0;
}

// tile counting-sort scatter: stage bucket-ordered in LDS, burst-flush coalesced.
// packed = (dst_local << sbits) | src
__global__ void __launch_bounds__(BLK) k_scatter(const int* __restrict__ src,
                                                 const int* __restrict__ dst,
                                                 const int* __restrict__ offs,
                                                 const int* __restrict__ base,
                                                 int* __restrict__ packed,
                                                 int E, int chunk, int K, int sbits) {
    __shared__ int cnt[KPAD];
    __shared__ int scn[KPAD];
    __shared__ int gstart[KPAD];
    __shared__ int cur[KPAD];
    __shared__ int stageval[TILE];
    __shared__ int stageaddr[TILE];
    int s = blockIdx.x;
    int tid = threadIdx.x;
    const int* orow = offs + (size_t)s * K;
    if (tid < K) cur[tid] = orow[tid] + base[tid];   // deterministic range start
    int lo = s * chunk, hi = min(E, lo + chunk);

    for (int tlo = lo; tlo < hi; tlo += TILE) {
        for (int k2 = tid; k2 < KPAD; k2 += BLK) cnt[k2] = 0;
        __syncthreads();

        int kk[EPT], rr[EPT], vv[EPT];
#pragma unroll
        for (int j = 0; j < EPT; ++j) {
            int i = tlo + j * BLK + tid;
            kk[j] = -1;
            if (i < hi) {
                int d = ntload(dst + i);
                int sc = ntload(src + i);
                kk[j] = ((unsigned)d) >> BSHIFT;
                vv[j] = ((d & (BSIZE - 1)) << sbits) | sc;
                rr[j] = atomicAdd(&cnt[kk[j]], 1);
            }
        }
        __syncthreads();

        // block-wide exclusive scan over cnt (KPAD == BLK)
        int c = cnt[tid];
        scn[tid] = c;
        __syncthreads();
        for (int off = 1; off < KPAD; off <<= 1) {
            int u = (tid >= off) ? scn[tid - off] : 0;
            __syncthreads();
            scn[tid] += u;
            __syncthreads();
        }
        scn[tid] -= c;                 // exclusive
        gstart[tid] = cur[tid];        // reserve global range for this tile
        cur[tid] += c;
        __syncthreads();

        // stage bucket-ordered
#pragma unroll
        for (int j = 0; j < EPT; ++j) {
            if (kk[j] >= 0) {
                int idx = scn[kk[j]] + rr[j];
                stageval[idx]  = vv[j];
                stageaddr[idx] = gstart[kk[j]] + rr[j];
            }
        }
        __syncthreads();

        // burst flush: consecutive threads -> consecutive addresses per segment
        int tot = min(hi - tlo, TILE);
        for (int i2 = tid; i2 < tot; i2 += BLK)
            packed[stageaddr[i2]] = stageval[i2];
        __syncthreads();
    }
}

// ---------------- aggregation passes (grid = K*M, private LDS tiles) -------

// degree counts -> degpart[b][BSIZE]
__global__ void k_deg(const int* __restrict__ packed, const int* __restrict__ base,
                      int M, int* __restrict__ degpart, int sbits) {
    __shared__ int cnt[BSIZE];
    int b = blockIdx.x;
    int k = b / M, m = b - k * M;
    for (int i = threadIdx.x; i < BSIZE; i += BLK) cnt[i] = 0;
    __syncthreads();
    int lo = base[k], len = base[k + 1] - lo;
    int l0 = lo + (int)(((long long)len * m) / M);
    int l1 = lo + (int)(((long long)len * (m + 1)) / M);
    int a0 = min((l0 + 3) & ~3, l1);
    int a1 = max(l1 & ~3, a0);
    for (int i = l0 + threadIdx.x; i < a0; i += BLK)
        atomicAdd(&cnt[((unsigned)ntload(packed + i)) >> sbits], 1);
    for (int i = a0 + 4 * threadIdx.x; i < a1; i += 4 * BLK) {
        iv4 q = ntload4(packed + i);
        atomicAdd(&cnt[((unsigned)q.x) >> sbits], 1);
        atomicAdd(&cnt[((unsigned)q.y) >> sbits], 1);
        atomicAdd(&cnt[((unsigned)q.z) >> sbits], 1);
        atomicAdd(&cnt[((unsigned)q.w) >> sbits], 1);
    }
    for (int i = a1 + threadIdx.x; i < l1; i += BLK)
        atomicAdd(&cnt[((unsigned)ntload(packed + i)) >> sbits], 1);
    __syncthreads();
    int* outp = degpart + (size_t)b * BSIZE;
    for (int i = threadIdx.x; i < BSIZE; i += BLK) outp[i] = cnt[i];
}

// sum p[src] into private LDS tile -> partial[b][BSIZE][2]
__global__ void k_agg(const int* __restrict__ packed, const int* __restrict__ base,
                      int M, const float2* __restrict__ pin, float* __restrict__ partial,
                      int sbits, int smask) {
    __shared__ float acc[BSIZE * 2];
    int b = blockIdx.x;
    int k = b / M, m = b - k * M;
    for (int i = threadIdx.x; i < BSIZE * 2; i += BLK) acc[i] = 0.f;
    __syncthreads();
    int lo = base[k], len = base[k + 1] - lo;
    int l0 = lo + (int)(((long long)len * m) / M);
    int l1 = lo + (int)(((long long)len * (m + 1)) / M);
    int a0 = min((l0 + 3) & ~3, l1);
    int a1 = max(l1 & ~3, a0);
    for (int i = l0 + threadIdx.x; i < a0; i += BLK) {
        unsigned v = (unsigned)ntload(packed + i);
        float2 pv = pin[v & smask];
        int l = v >> sbits;
        atomicAdd(&acc[2 * l], pv.x);
        atomicAdd(&acc[2 * l + 1], pv.y);
    }
    for (int i = a0 + 4 * threadIdx.x; i < a1; i += 4 * BLK) {
        iv4 q = ntload4(packed + i);
        unsigned v0 = q.x, v1 = q.y, v2 = q.z, v3 = q.w;
        float2 e0 = pin[v0 & smask];    // 4 independent gathers in flight
        float2 e1 = pin[v1 & smask];
        float2 e2 = pin[v2 & smask];
        float2 e3 = pin[v3 & smask];
        int l0i = v0 >> sbits, l1i = v1 >> sbits, l2i = v2 >> sbits, l3i = v3 >> sbits;
        atomicAdd(&acc[2 * l0i], e0.x); atomicAdd(&acc[2 * l0i + 1], e0.y);
        atomicAdd(&acc[2 * l1i], e1.x); atomicAdd(&acc[2 * l1i + 1], e1.y);
        atomicAdd(&acc[2 * l2i], e2.x); atomicAdd(&acc[2 * l2i + 1], e2.y);
        atomicAdd(&acc[2 * l3i], e3.x); atomicAdd(&acc[2 * l3i + 1], e3.y);
    }
    for (int i = a1 + threadIdx.x; i < l1; i += BLK) {
        unsigned v = (unsigned)ntload(packed + i);
        float2 pv = pin[v & smask];
        int l = v >> sbits;
        atomicAdd(&acc[2 * l], pv.x);
        atomicAdd(&acc[2 * l + 1], pv.y);
    }
    __syncthreads();
    float* outp = partial + (size_t)b * (BSIZE * 2);
    for (int i = threadIdx.x * 4; i < BSIZE * 2; i += BLK * 4)
        *(float4*)(outp + i) = *(const float4*)(acc + i);
}

// ---------------- node epilogues ----------------

__global__ void k_node1(const int* __restrict__ degpart, int M,
                        const float* __restrict__ x, const float* __restrict__ W1,
                        float* __restrict__ dinv, float2* __restrict__ p1, int N) {
    int i = blockIdx.x * BLK + threadIdx.x;
    if (i >= N) return;
    int k = i >> BSHIFT, l = i & (BSIZE - 1);
    int c = 0;
    for (int m = 0; m < M; ++m) c += degpart[((size_t)(k * M + m)) * BSIZE + l];
    float di = rsqrtf((float)c + 1.0f);
    dinv[i] = di;
    float2 xv = ((const float2*)x)[i];
    float w00 = W1[0], w01 = W1[1], w10 = W1[2], w11 = W1[3];
    p1[i] = make_float2(di * (xv.x * w00 + xv.y * w10),
                        di * (xv.x * w01 + xv.y * w11));
}

__global__ void k_node_mid(const float* __restrict__ partial, int M,
                           const float* __restrict__ dinv, const float2* __restrict__ pin,
                           const float* __restrict__ b, const float* __restrict__ W,
                           float2* __restrict__ pout, int N) {
    int i = blockIdx.x * BLK + threadIdx.x;
    if (i >= N) return;
    int k = i >> BSHIFT, l = i & (BSIZE - 1);
    float2 self = pin[i];
    float ax = self.x, ay = self.y;
    for (int m = 0; m < M; ++m) {
        const float* pp = partial + ((size_t)(k * M + m)) * (BSIZE * 2) + 2 * l;
        ax += pp[0]; ay += pp[1];
    }
    float di = dinv[i];
    float h0 = fmaxf(fmaf(di, ax, b[0]), 0.f);
    float h1 = fmaxf(fmaf(di, ay, b[1]), 0.f);
    float w00 = W[0], w01 = W[1], w10 = W[2], w11 = W[3];
    pout[i] = make_float2(di * (h0 * w00 + h1 * w10),
                          di * (h0 * w01 + h1 * w11));
}

__global__ void k_out_init(float* __restrict__ out, const float* __restrict__ br, int G) {
    int i = blockIdx.x * BLK + threadIdx.x;
    if (i < G) out[i] = br[0];
}

// final layer epilogue fused with global_add_pool (sorted batch keys)
__global__ void k_node_final(const float* __restrict__ partial, int M,
                             const float* __restrict__ dinv, const float2* __restrict__ pin,
                             const float* __restrict__ b, const float* __restrict__ Wr,
                             const int* __restrict__ batch, float* __restrict__ out, int N) {
    int i = blockIdx.x * BLK + threadIdx.x;
    bool valid = i < N;
    float s = 0.f;
    int key = -1;
    if (valid) {
        int k = i >> BSHIFT, l = i & (BSIZE - 1);
        float2 self = pin[i];
        float ax = self.x, ay = self.y;
        for (int m = 0; m < M; ++m) {
            const float* pp = partial + ((size_t)(k * M + m)) * (BSIZE * 2) + 2 * l;
            ax += pp[0]; ay += pp[1];
        }
        float di = dinv[i];
        float h0 = fmaxf(fmaf(di, ax, b[0]), 0.f);
        float h1 = fmaxf(fmaf(di, ay, b[1]), 0.f);
        s = fmaf(h0, Wr[0], h1 * Wr[1]);
        key = batch[i];
    }
    int lane = threadIdx.x & 63;
    for (int off = 1; off < 64; off <<= 1) {
        float s2 = __shfl_down(s, off);
        int k2 = __shfl_down(key, off);
        if (lane + off < 64 && k2 == key) s += s2;
    }
    int kprev = __shfl_up(key, 1);
    if (valid && (lane == 0 || kprev != key)) unsafeAtomicAdd(&out[key], s);
}

// ---------------- launch ----------------

extern "C" void kernel_launch(void* const* d_in, const int* in_sizes, int n_in,
                              void* d_out, int out_size, void* d_ws, size_t ws_size,
                              hipStream_t stream) {
    const float* x    = (const float*)d_in[0];
    const int*   ei   = (const int*)d_in[1];
    const int*   batch= (const int*)d_in[2];
    const float* W1   = (const float*)d_in[3];
    const float* b1   = (const float*)d_in[4];
    const float* W2   = (const float*)d_in[5];
    const float* b2   = (const float*)d_in[6];
    const float* W3   = (const float*)d_in[7];
    const float* b3   = (const float*)d_in[8];
    const float* Wr   = (const float*)d_in[9];
    const float* br   = (const float*)d_in[10];
    float* out = (float*)d_out;

    int N = in_sizes[0] / 2;
    int E = in_sizes[1] / 2;
    int G = out_size;
    const int* src = ei;
    const int* dst = ei + E;

    int K = (N + BSIZE - 1) >> BSHIFT;
    if (K > KPAD) return;                       // scatter scan width limit
    int S = NSLICE;
    int chunk = (E + S - 1) / S;

    int sbits = 1;
    while ((1 << sbits) < N) ++sbits;           // src bit width (18 for N=200000)
    if (sbits + BSHIFT > 32) return;
    int smask = (1 << sbits) - 1;

    // pick M (sub-blocks per bucket) to fit workspace
    int M = 16;
    size_t need;
    for (;;) {
        need = (((size_t)E * 4 + 15) & ~(size_t)15)
             + (((size_t)S * K * 4 + 15) & ~(size_t)15)
             + (((size_t)(K + 1) * 4 + 15) & ~(size_t)15)
             + (((size_t)K * 4 + 15) & ~(size_t)15)
             + (((size_t)K * M * BSIZE * 2 * 4 + 15) & ~(size_t)15)
             + (((size_t)N * 4 + 15) & ~(size_t)15)
             + 2 * (((size_t)N * 8 + 15) & ~(size_t)15);
        if (need <= ws_size || M == 1) break;
        M >>= 1;
    }
    if (need > ws_size) return;

    char* w = (char*)d_ws;
    size_t off = 0;
    auto carve = [&](size_t bytes) { void* p = w + off; off += (bytes + 15) & ~(size_t)15; return p; };
    int*    packed  = (int*)carve((size_t)E * 4);
    int*    hpart   = (int*)carve((size_t)S * K * 4);
    int*    basep   = (int*)carve((size_t)(K + 1) * 4);
    int*    totals  = (int*)carve((size_t)K * 4);
    float*  aggpart = (float*)carve((size_t)K * M * BSIZE * 2 * 4);
    float*  dinv    = (float*)carve((size_t)N * 4);
    float2* pA      = (float2*)carve((size_t)N * 8);
    float2* pB      = (float2*)carve((size_t)N * 8);
    int*    degpart = (int*)aggpart;            // reuse: consumed before first k_agg

    int NB = (N + BLK - 1) / BLK;
    int GB = (G + BLK - 1) / BLK;
    size_t smemK = (size_t)K * 4;
    int KM = K * M;

    // build bucketed edge list
    k_hist   <<<S, BLK, smemK, stream>>>(dst, hpart, E, chunk, K);
    k_colscan<<<K, NSLICE, 0, stream>>>(hpart, totals, K);
    k_base   <<<1, SCAN_T, 0, stream>>>(totals, basep, K);
    k_scatter<<<S, BLK, 0, stream>>>(src, dst, hpart, basep, packed, E, chunk, K, sbits);

    // degree -> dinv, p1
    k_deg   <<<KM, BLK, 0, stream>>>(packed, basep, M, degpart, sbits);
    k_node1 <<<NB, BLK, 0, stream>>>(degpart, M, x, W1, dinv, pA, N);

    // layer 1
    k_agg     <<<KM, BLK, 0, stream>>>(packed, basep, M, pA, aggpart, sbits, smask);
    k_node_mid<<<NB, BLK, 0, stream>>>(aggpart, M, dinv, pA, b1, W2, pB, N);
    // layer 2
    k_agg     <<<KM, BLK, 0, stream>>>(packed, basep, M, pB, aggpart, sbits, smask);
    k_node_mid<<<NB, BLK, 0, stream>>>(aggpart, M, dinv, pB, b2, W3, pA, N);
    // layer 3 + pool
    k_agg     <<<KM, BLK, 0, stream>>>(packed, basep, M, pA, aggpart, sbits, smask);
    k_out_init<<<GB, BLK, 0, stream>>>(out, br, G);
    k_node_final<<<NB, BLK, 0, stream>>>(aggpart, M, dinv, pA, b3, Wr, batch, out, N);
}